// Round 7
// baseline (202.308 us; speedup 1.0000x reference)
//
#include <hip/hip_runtime.h>
#include <hip/hip_bf16.h>
#include <math.h>

typedef short bf16x8 __attribute__((ext_vector_type(8)));
typedef float f32x4 __attribute__((ext_vector_type(4)));
typedef unsigned short u16;

__device__ inline float b2f(u16 h) {
    unsigned int u = ((unsigned int)h) << 16;
    float f;
    __builtin_memcpy(&f, &u, 4);
    return f;
}

__device__ inline u16 f2b(float f) {
    unsigned int u;
    __builtin_memcpy(&u, &f, 4);
    unsigned int lsb = (u >> 16) & 1u;
    u += 0x7fffu + lsb;
    return (u16)(u >> 16);
}

// async 16B global -> LDS (wave-uniform base + lane*16 at all call sites)
__device__ __forceinline__ void gl2lds16(const u16* g, u16* l) {
    __builtin_amdgcn_global_load_lds(
        (const __attribute__((address_space(1))) unsigned int*)g,
        (__attribute__((address_space(3))) unsigned int*)l,
        16, 0, 0);
}

#define PITCH 72   // wtrans scratch pitch

// log2(e) / 8  (softmax temperature sqrt(64)=8 folded into Q projection)
#define QSCALE 0.18033688011112042f

// ---------------------------------------------------------------------------
// Launch 1: cvt (blocks 0..8191) U wtrans (blocks 8192..8447).
// Independent inputs -> one launch, no inter-stage bubble.
// ---------------------------------------------------------------------------
__global__ __launch_bounds__(256) void cvtw_kernel(const float* __restrict__ x,
                                                   u16* __restrict__ xb,
                                                   const float* __restrict__ w0,
                                                   const float* __restrict__ w1,
                                                   const float* __restrict__ w2,
                                                   const float* __restrict__ w3,
                                                   u16* __restrict__ wt) {
    __shared__ u16 T[64 * PITCH];
    int tid = threadIdx.x;
    if (blockIdx.x < 8192) {            // ---- cvt: x f32 -> bf16
        int idx = blockIdx.x * 256 + tid;   // 2,097,152 float4s
        float4 v = ((const float4*)x)[idx];
        ushort4 o;
        o.x = f2b(v.x); o.y = f2b(v.y); o.z = f2b(v.z); o.w = f2b(v.w);
        ((ushort4*)xb)[idx] = o;
        return;
    }
    // ---- wtrans: transpose+convert four 512x512 f32 weights to WT[n][k]
    int t5 = blockIdx.x - 8192;         // 0..255
    int bx = t5 & 7, by = (t5 >> 3) & 7, bz = t5 >> 6;
    const float* W = bz == 0 ? w0 : bz == 1 ? w1 : bz == 2 ? w2 : w3;
    u16* WT = wt + (size_t)bz * 262144;
    int nB = bx * 64, kB = by * 64;
#pragma unroll
    for (int t = 0; t < 4; ++t) {
        int e = tid + t * 256;
        int r = e >> 4, c4 = (e & 15) * 4;
        float4 v = *(const float4*)(&W[(size_t)(kB + r) * 512 + nB + c4]);
        u16* dst = &T[r * PITCH + c4];
        dst[0] = f2b(v.x); dst[1] = f2b(v.y); dst[2] = f2b(v.z); dst[3] = f2b(v.w);
    }
    __syncthreads();
    int n = tid & 63, kg = tid >> 6;
#pragma unroll
    for (int p = 0; p < 2; ++p) {
        int k0 = (kg + p * 4) * 8;
        u16 tmp[8];
#pragma unroll
        for (int i = 0; i < 8; ++i) tmp[i] = T[(k0 + i) * PITCH + n];
        *(int4*)(&WT[(size_t)(nB + n) * 512 + kB + k0]) = *(int4*)tmp;
    }
}

// ---------------------------------------------------------------------------
// pool body: TF avg-pool 3x3/s2 SAME (divide by valid count), bf16 in/out.
// ---------------------------------------------------------------------------
__device__ __forceinline__ void pool_body(int idx, const u16* __restrict__ xb,
                                          u16* __restrict__ xp) {
    int c8 = idx & 63;
    int j = (idx >> 6) & 31;
    int i = (idx >> 11) & 31;
    int b = idx >> 16;
    int r0 = 2 * i, c0 = 2 * j;
    int rmax = min(r0 + 3, 64), cmax = min(c0 + 3, 64);
    float acc[8] = {};
    for (int r = r0; r < rmax; ++r)
        for (int cc = c0; cc < cmax; ++cc) {
            bf16x8 v = *(const bf16x8*)(
                &xb[(size_t)((((b << 6) + r) << 6) + cc) * 512 + c8 * 8]);
#pragma unroll
            for (int t = 0; t < 8; ++t) acc[t] += b2f(((const u16*)&v)[t]);
        }
    float inv = 1.f / (float)((rmax - r0) * (cmax - c0));
    u16 o[8];
#pragma unroll
    for (int t = 0; t < 8; ++t) o[t] = f2b(acc[t] * inv);
    *(int4*)(&xp[(size_t)idx * 8]) = *(int4*)o;
}

// ---------------------------------------------------------------------------
// GEMM body v2: tile 64xBN, BK=64, 4 waves, DOUBLE-BUFFERED LDS with the
// T3 single-barrier 2-phase schedule:
//     STAGE(next) -> COMPUTE(cur) -> s_waitcnt vmcnt(0) -> s_barrier
// Loads issued before compute have the whole MFMA phase (~600 cy) to land;
// the end-of-iter drain is nearly free (was: stage -> full drain -> compute,
// 8 exposed ~400-cy drains/block -- the round-4..6 A/Bs eliminated locality
// and occupancy as causes; this is the remaining structural stall).
// Race-safety: compute of buf X and the next stage into X are separated by
// the end-of-iter barrier. Staging is global_load_lds with addresses
// recomputed from kk -> no persistent VGPR state (round-2's spill mechanism
// is absent). OM=0: bf16*oscale. OM=1: f32+residual. OM=3: fused K|V.
// XCD remap kept: bid = nBlk*GY + mBlk, GY % 8 == 0.
// ---------------------------------------------------------------------------
template <int OM, int BN, int GY>
__device__ __forceinline__ void gemm_body(int bid,
                                          const u16* __restrict__ A,
                                          const u16* __restrict__ WT,
                                          const float* __restrict__ bias,
                                          const float* __restrict__ bias2res,
                                          void* __restrict__ Cv,
                                          void* __restrict__ Cv2,
                                          float oscale,
                                          u16* At, u16* Bt) {
    int tid = threadIdx.x, lane = tid & 63, wave = tid >> 6;
    int q = lane >> 4, l16 = lane & 15;
    constexpr int MI = (BN == 128) ? 2 : 1;
    int wm, wn;
    if constexpr (BN == 128) { wm = wave & 1; wn = wave >> 1; }
    else                     { wm = wave;     wn = 0; }
    int nBlk = bid / GY;
    int mBlk = bid - nBlk * GY;
    int nBase = nBlk * BN, mBase = mBlk * 64;
    f32x4 acc[MI][4] = {};

    auto stage = [&](int buf, int kk) {
        u16* Ab = At + buf * (64 * 64);
        u16* Bb = Bt + buf * (BN * 64);
#pragma unroll
        for (int t = 0; t < 2; ++t) {             // At: 512 chunk slots
            int c = tid + t * 256;
            int m = c >> 3, kc = (c & 7) ^ (m & 7);
            gl2lds16(&A[(size_t)(mBase + m) * 512 + kk + kc * 8], &Ab[c * 8]);
        }
#pragma unroll
        for (int t = 0; t < BN / 32; ++t) {       // Bt: BN*8 chunk slots
            int c = tid + t * 256;
            int m = c >> 3, kc = (c & 7) ^ (m & 7);
            gl2lds16(&WT[(size_t)(nBase + m) * 512 + kk + kc * 8], &Bb[c * 8]);
        }
    };

    auto compute = [&](int buf) {
        const u16* Ab = At + buf * (64 * 64);
        const u16* Bb = Bt + buf * (BN * 64);
#pragma unroll
        for (int ds = 0; ds < 2; ++ds) {
            bf16x8 a[MI], b[4];
#pragma unroll
            for (int i = 0; i < MI; ++i) {
                int ma = (BN == 128 ? wm * 32 : wm * 16) + i * 16 + l16;
                a[i] = *(const bf16x8*)(&Ab[ma * 64 + ((((ds << 2) + q) ^ (ma & 7)) << 3)]);
            }
#pragma unroll
            for (int j = 0; j < 4; ++j) {
                int nb = wn * 64 + j * 16 + l16;
                b[j] = *(const bf16x8*)(&Bb[nb * 64 + ((((ds << 2) + q) ^ (nb & 7)) << 3)]);
            }
#pragma unroll
            for (int i = 0; i < MI; ++i)
#pragma unroll
                for (int j = 0; j < 4; ++j)
                    acc[i][j] = __builtin_amdgcn_mfma_f32_16x16x32_bf16(a[i], b[j], acc[i][j], 0, 0, 0);
        }
    };

    stage(0, 0);
    asm volatile("s_waitcnt vmcnt(0)" ::: "memory");
    __builtin_amdgcn_s_barrier();
    int cur = 0;
#pragma unroll 1
    for (int kk = 64; kk < 512; kk += 64) {
        stage(cur ^ 1, kk);                       // issue next tile's loads
        compute(cur);                             // ...they land under MFMA
        asm volatile("s_waitcnt vmcnt(0)" ::: "memory");
        __builtin_amdgcn_s_barrier();
        cur ^= 1;
    }
    compute(cur);                                 // tile 7: already drained

    bool isK = (OM != 3) || (nBase < 512);
#pragma unroll
    for (int j = 0; j < 4; ++j) {
        int col = nBase + wn * 64 + j * 16 + l16;
        float bv;
        if constexpr (OM == 3) bv = isK ? bias[col] : bias2res[col - 512];
        else bv = bias[col];
#pragma unroll
        for (int i = 0; i < MI; ++i) {
#pragma unroll
            for (int r = 0; r < 4; ++r) {
                int row = mBase + (BN == 128 ? wm * 32 : wm * 16) + i * 16 + q * 4 + r;
                float v = acc[i][j][r] + bv;
                if constexpr (OM == 1) {
                    v += bias2res[(size_t)row * 512 + col];
                    ((float*)Cv)[(size_t)row * 512 + col] = v;
                } else if constexpr (OM == 0) {
                    ((u16*)Cv)[(size_t)row * 512 + col] = f2b(v * oscale);
                } else {
                    if (isK) {
                        ((u16*)Cv)[(size_t)row * 512 + col] = f2b(v);
                    } else {
                        int colv = col - 512;
                        int g = row >> 7, m2 = ((row & 127) << 3) + (colv >> 6), d = colv & 63;
                        ((u16*)Cv2)[(size_t)((g << 6) + d) * 1024 + m2] = f2b(v);
                    }
                }
            }
        }
    }
}

// ---------------------------------------------------------------------------
// Launch 2: Q-GEMM (blocks 0..1023) U pool (blocks 1024..2047). LDS 48 KB
// (double-buffered) -> 3 blocks/CU, VGPR cap 168.
// ---------------------------------------------------------------------------
__global__ __launch_bounds__(256, 3) void qpool_kernel(const u16* __restrict__ xb,
                                                       const u16* __restrict__ wTq,
                                                       const float* __restrict__ b_q,
                                                       u16* __restrict__ Qw,
                                                       u16* __restrict__ xp) {
    __shared__ __align__(16) u16 At[2 * 64 * 64];
    __shared__ __align__(16) u16 Bt[2 * 128 * 64];
    int gid = blockIdx.x;
    if (gid < 1024) {
        gemm_body<0, 128, 256>(gid, xb, wTq, b_q, nullptr, Qw, nullptr, QSCALE, At, Bt);
    } else {
        pool_body((gid - 1024) * 256 + threadIdx.x, xb, xp);
    }
}

// Launch 3: fused K|V projection, tile 64x64 -> 1024 blocks; dbuf LDS 32 KB
// -> 4 blocks/CU.
__global__ __launch_bounds__(256, 4) void gemm_kv_kernel(const u16* __restrict__ xp,
                                                         const u16* __restrict__ wTkv,
                                                         const float* __restrict__ b_k,
                                                         const float* __restrict__ b_v,
                                                         u16* __restrict__ Kw,
                                                         u16* __restrict__ VwT) {
    __shared__ __align__(16) u16 At[2 * 64 * 64];
    __shared__ __align__(16) u16 Bt[2 * 64 * 64];
    gemm_body<3, 64, 64>(blockIdx.x, xp, wTkv, b_k, b_v, Kw, VwT, 1.0f, At, Bt);
}

// Launch 5: output projection + f32 residual. Dbuf LDS 48 KB -> 3 blocks/CU.
__global__ __launch_bounds__(256, 3) void gemm_o_kernel(const u16* __restrict__ Ow,
                                                        const u16* __restrict__ wTo,
                                                        const float* __restrict__ b_o,
                                                        const float* __restrict__ xres,
                                                        float* __restrict__ out) {
    __shared__ __align__(16) u16 At[2 * 64 * 64];
    __shared__ __align__(16) u16 Bt[2 * 128 * 64];
    gemm_body<1, 128, 256>(blockIdx.x, Ow, wTo, b_o, xres, out, nullptr, 1.0f, At, Bt);
}

// ---------------------------------------------------------------------------
// Launch 4: flash attention per group, S^T formulation.
// Harness-verified single-buffer structure; VALU cut (exp2 builtin + cvt_pk);
// XCD pinning (g = blockIdx.x -> XCD = g&7; FETCH 41->12 MB confirmed);
// s_setprio(1) around MFMA clusters. LDS 40960 B -> 4 blocks/CU; grid 1024.
// ---------------------------------------------------------------------------
__global__ __launch_bounds__(256, 4) void attn_kernel(const u16* __restrict__ Q,
                                                      const u16* __restrict__ K,
                                                      const u16* __restrict__ VT_g,
                                                      u16* __restrict__ O) {
    int g = blockIdx.x;       // XCD = g & 7 (round-robin by linear id)
    int qtile = blockIdx.y;   // 0..31
    const u16* Qg = Q + (size_t)g * 262144;
    const u16* Kg = K + (size_t)g * 65536;
    const u16* Vt = VT_g + (size_t)g * 65536;   // [d][m], pitch 1024
    u16* Og = O + (size_t)g * 262144;

    __shared__ __align__(16) u16 Kt[128 * 64];    // XOR-8 swizzled [m][d]
    __shared__ __align__(16) u16 VTs[64 * 128];   // XOR-16 swizzled [d][m]
    __shared__ __align__(16) u16 Pt[64 * 64];     // XOR-4dw swizzled [n][m-half]

    int tid = threadIdx.x, lane = tid & 63, wave = tid >> 6;
    int q = lane >> 4, l16 = lane & 15;
    int n0 = qtile * 128;
    int pkey = (l16 & 7) << 2;            // dword-XOR key for Pt
    int prow = (wave * 16 + l16) * 32;    // Pt row base (dwords)
    int* Pt32 = (int*)Pt;

    bf16x8 qf[2][2];
#pragma unroll
    for (int s = 0; s < 2; ++s)
#pragma unroll
        for (int ds = 0; ds < 2; ++ds)
            qf[s][ds] = *(const bf16x8*)(
                &Qg[(size_t)(n0 + s * 64 + wave * 16 + l16) * 64 + ds * 32 + q * 8]);

    f32x4 oacc[2][4] = {};
    float rsum[2] = {0.f, 0.f};

    for (int kb = 0; kb < 8; ++kb) {
        __syncthreads();
#pragma unroll
        for (int t = 0; t < 4; ++t) {
            int c = wave * 64 + lane + t * 256;       // slot 0..1023
            {   // K tile: 128 m-rows x 64 d, XOR-8
                int m = c >> 3, kc = (c & 7) ^ (m & 7);
                gl2lds16(&Kg[(size_t)(kb * 128 + m) * 64 + kc * 8], &Kt[c * 8]);
            }
            {   // V^T tile: 64 d-rows x 128 m, XOR-16
                int d = c >> 4, mc = (c & 15) ^ (d & 15);
                gl2lds16(&Vt[(size_t)d * 1024 + kb * 128 + mc * 8], &VTs[c * 8]);
            }
        }
        __syncthreads();

#pragma unroll
        for (int h = 0; h < 2; ++h) {
#pragma unroll
            for (int s = 0; s < 2; ++s) {
                // S^T block; p = exp2(z); packed b64 write to Pt[n][m]
#pragma unroll
                for (int cb = 0; cb < 4; ++cb) {
                    int m = h * 64 + cb * 16 + l16;
                    bf16x8 kf0 = *(bf16x8*)(&Kt[m * 64 + ((q ^ (m & 7)) << 3)]);
                    bf16x8 kf1 = *(bf16x8*)(&Kt[m * 64 + (((4 + q) ^ (m & 7)) << 3)]);
                    f32x4 z = {};
                    __builtin_amdgcn_s_setprio(1);
                    z = __builtin_amdgcn_mfma_f32_16x16x32_bf16(kf0, qf[s][0], z, 0, 0, 0);
                    z = __builtin_amdgcn_mfma_f32_16x16x32_bf16(kf1, qf[s][1], z, 0, 0, 0);
                    __builtin_amdgcn_s_setprio(0);
                    float p0 = __builtin_amdgcn_exp2f(z[0]);
                    float p1 = __builtin_amdgcn_exp2f(z[1]);
                    float p2 = __builtin_amdgcn_exp2f(z[2]);
                    float p3 = __builtin_amdgcn_exp2f(z[3]);
                    rsum[s] += (p0 + p1) + (p2 + p3);
                    unsigned w0, w1;
                    asm("v_cvt_pk_bf16_f32 %0, %1, %2" : "=v"(w0) : "v"(p0), "v"(p1));
                    asm("v_cvt_pk_bf16_f32 %0, %1, %2" : "=v"(w1) : "v"(p2), "v"(p3));
                    int2 w;
                    w.x = (int)w0;
                    w.y = (int)w1;
                    int pd = (cb * 8 + q * 2) ^ pkey;
                    *(int2*)(&Pt32[prow + pd]) = w;
                }
                // O += P V (same wave wrote Pt rows; DS in-order, no barrier)
#pragma unroll
                for (int ds = 0; ds < 2; ++ds) {
                    int pd = (ds * 16 + q * 4) ^ pkey;
                    bf16x8 ap = *(bf16x8*)(&Pt32[prow + pd]);
                    __builtin_amdgcn_s_setprio(1);
#pragma unroll
                    for (int db = 0; db < 4; ++db) {
                        int dd = db * 16 + l16;
                        int jj = h * 8 + ds * 4 + q;
                        bf16x8 vb = *(bf16x8*)(&VTs[dd * 128 + ((jj ^ (dd & 15)) << 3)]);
                        oacc[s][db] = __builtin_amdgcn_mfma_f32_16x16x32_bf16(ap, vb, oacc[s][db], 0, 0, 0);
                    }
                    __builtin_amdgcn_s_setprio(0);
                }
            }
        }
    }

    // epilogue: rsum lives at row n=l16 (partial over quads) -> reduce over
    // quads, then fetch row (q*4+r)'s total via shfl, normalize, store.
#pragma unroll
    for (int s = 0; s < 2; ++s) {
        float v = rsum[s];
        v += __shfl_xor(v, 16, 64);
        v += __shfl_xor(v, 32, 64);
        rsum[s] = v;
    }
    float inv[2][4];
#pragma unroll
    for (int s = 0; s < 2; ++s)
#pragma unroll
        for (int r = 0; r < 4; ++r)
            inv[s][r] = 1.f / __shfl(rsum[s], q * 4 + r, 64);
#pragma unroll
    for (int s = 0; s < 2; ++s)
#pragma unroll
        for (int db = 0; db < 4; ++db)
#pragma unroll
            for (int r = 0; r < 4; ++r) {
                int row = n0 + s * 64 + wave * 16 + q * 4 + r;
                Og[(size_t)row * 64 + db * 16 + l16] = f2b(oacc[s][db][r] * inv[s][r]);
            }
}

// ---------------------------------------------------------------------------
extern "C" void kernel_launch(void* const* d_in, const int* in_sizes, int n_in,
                              void* d_out, int out_size, void* d_ws, size_t ws_size,
                              hipStream_t stream) {
    const float* x   = (const float*)d_in[0];
    const float* w_q = (const float*)d_in[1];
    const float* b_q = (const float*)d_in[2];
    const float* w_k = (const float*)d_in[3];
    const float* b_k = (const float*)d_in[4];
    const float* w_v = (const float*)d_in[5];
    const float* b_v = (const float*)d_in[6];
    const float* w_o = (const float*)d_in[7];
    const float* b_o = (const float*)d_in[8];
    float* out = (float*)d_out;

    char* ws = (char*)d_ws;
    u16* xb  = (u16*)(ws);                        // 16 MB (16384,512) bf16
    u16* xp  = (u16*)(ws + (16ull << 20));        //  4 MB (4096,512)
    u16* Qw  = (u16*)(ws + (20ull << 20));        // 16 MB (16384,512)
    u16* Kw  = (u16*)(ws + (36ull << 20));        //  4 MB (4096,512)
    u16* VwT = (u16*)(ws + (40ull << 20));        //  4 MB 32x(64,1024)
    u16* wT  = (u16*)(ws + (44ull << 20));        //  2 MB: 4 x 512x512 bf16
    u16* Ow  = xb;  // alias: xb's last readers (Q-GEMM+pool, L2) precede attn's write (L4)

    // L1: cvt U wtrans
    cvtw_kernel<<<8448, 256, 0, stream>>>(x, xb, w_q, w_k, w_v, w_o, wT);
    // L2: Q projection (scaled by log2(e)/8) U pool
    qpool_kernel<<<2048, 256, 0, stream>>>(xb, wT, b_q, Qw, xp);
    // L3: fused K|V projection
    gemm_kv_kernel<<<1024, 256, 0, stream>>>(xp, wT + 262144, b_k, b_v, Kw, VwT);
    // L4: attention: 32 groups (x: XCD-pinned) x 32 q-tiles (y)
    attn_kernel<<<dim3(32, 32), 256, 0, stream>>>(Qw, Kw, VwT, Ow);
    // L5: output projection + f32 residual
    gemm_o_kernel<<<1024, 256, 0, stream>>>(Ow, wT + 786432, b_o, x, out);
}

// Round 8
// 199.900 us; speedup vs baseline: 1.0120x; 1.0120x over previous
//
#include <hip/hip_runtime.h>
#include <hip/hip_bf16.h>
#include <math.h>

typedef short bf16x8 __attribute__((ext_vector_type(8)));
typedef float f32x4 __attribute__((ext_vector_type(4)));
typedef unsigned short u16;

__device__ inline float b2f(u16 h) {
    unsigned int u = ((unsigned int)h) << 16;
    float f;
    __builtin_memcpy(&f, &u, 4);
    return f;
}

__device__ inline u16 f2b(float f) {
    unsigned int u;
    __builtin_memcpy(&u, &f, 4);
    unsigned int lsb = (u >> 16) & 1u;
    u += 0x7fffu + lsb;
    return (u16)(u >> 16);
}

// async 16B global -> LDS (wave-uniform base + lane*16 at all call sites)
__device__ __forceinline__ void gl2lds16(const u16* g, u16* l) {
    __builtin_amdgcn_global_load_lds(
        (const __attribute__((address_space(1))) unsigned int*)g,
        (__attribute__((address_space(3))) unsigned int*)l,
        16, 0, 0);
}

#define PITCH 72   // wtrans scratch pitch

// log2(e) / 8  (softmax temperature sqrt(64)=8 folded into Q projection)
#define QSCALE 0.18033688011112042f

// ---------------------------------------------------------------------------
// Launch 1: cvt (blocks 0..8191) U wtrans (blocks 8192..8447).
// ---------------------------------------------------------------------------
__global__ __launch_bounds__(256) void cvtw_kernel(const float* __restrict__ x,
                                                   u16* __restrict__ xb,
                                                   const float* __restrict__ w0,
                                                   const float* __restrict__ w1,
                                                   const float* __restrict__ w2,
                                                   const float* __restrict__ w3,
                                                   u16* __restrict__ wt) {
    __shared__ u16 T[64 * PITCH];
    int tid = threadIdx.x;
    if (blockIdx.x < 8192) {            // ---- cvt: x f32 -> bf16
        int idx = blockIdx.x * 256 + tid;   // 2,097,152 float4s
        float4 v = ((const float4*)x)[idx];
        ushort4 o;
        o.x = f2b(v.x); o.y = f2b(v.y); o.z = f2b(v.z); o.w = f2b(v.w);
        ((ushort4*)xb)[idx] = o;
        return;
    }
    // ---- wtrans: transpose+convert four 512x512 f32 weights to WT[n][k]
    int t5 = blockIdx.x - 8192;         // 0..255
    int bx = t5 & 7, by = (t5 >> 3) & 7, bz = t5 >> 6;
    const float* W = bz == 0 ? w0 : bz == 1 ? w1 : bz == 2 ? w2 : w3;
    u16* WT = wt + (size_t)bz * 262144;
    int nB = bx * 64, kB = by * 64;
#pragma unroll
    for (int t = 0; t < 4; ++t) {
        int e = tid + t * 256;
        int r = e >> 4, c4 = (e & 15) * 4;
        float4 v = *(const float4*)(&W[(size_t)(kB + r) * 512 + nB + c4]);
        u16* dst = &T[r * PITCH + c4];
        dst[0] = f2b(v.x); dst[1] = f2b(v.y); dst[2] = f2b(v.z); dst[3] = f2b(v.w);
    }
    __syncthreads();
    int n = tid & 63, kg = tid >> 6;
#pragma unroll
    for (int p = 0; p < 2; ++p) {
        int k0 = (kg + p * 4) * 8;
        u16 tmp[8];
#pragma unroll
        for (int i = 0; i < 8; ++i) tmp[i] = T[(k0 + i) * PITCH + n];
        *(int4*)(&WT[(size_t)(nB + n) * 512 + kB + k0]) = *(int4*)tmp;
    }
}

// ---------------------------------------------------------------------------
// pool body: TF avg-pool 3x3/s2 SAME (divide by valid count), bf16 in/out.
// ---------------------------------------------------------------------------
__device__ __forceinline__ void pool_body(int idx, const u16* __restrict__ xb,
                                          u16* __restrict__ xp) {
    int c8 = idx & 63;
    int j = (idx >> 6) & 31;
    int i = (idx >> 11) & 31;
    int b = idx >> 16;
    int r0 = 2 * i, c0 = 2 * j;
    int rmax = min(r0 + 3, 64), cmax = min(c0 + 3, 64);
    float acc[8] = {};
    for (int r = r0; r < rmax; ++r)
        for (int cc = c0; cc < cmax; ++cc) {
            bf16x8 v = *(const bf16x8*)(
                &xb[(size_t)((((b << 6) + r) << 6) + cc) * 512 + c8 * 8]);
#pragma unroll
            for (int t = 0; t < 8; ++t) acc[t] += b2f(((const u16*)&v)[t]);
        }
    float inv = 1.f / (float)((rmax - r0) * (cmax - c0));
    u16 o[8];
#pragma unroll
    for (int t = 0; t < 8; ++t) o[t] = f2b(acc[t] * inv);
    *(int4*)(&xp[(size_t)idx * 8]) = *(int4*)o;
}

// ---------------------------------------------------------------------------
// GEMM body (round-6 verified): tile 64xBN, BK=64, 4 waves, SINGLE-buffer
// LDS (round-7 A/B: explicit dbuf cost occupancy 4->3 and REGRESSED +5.5us;
// implicit wave-level overlap at 4 blocks/CU already hides the drain).
// XCD remap: bid = nBlk*GY + mBlk, GY % 8 == 0 -> A-panel sharers on one XCD.
// OM=0: bf16*oscale. OM=1: f32+residual. OM=3: fused K|V split at col 512.
// ---------------------------------------------------------------------------
template <int OM, int BN, int GY>
__device__ __forceinline__ void gemm_body(int bid,
                                          const u16* __restrict__ A,
                                          const u16* __restrict__ WT,
                                          const float* __restrict__ bias,
                                          const float* __restrict__ bias2res,
                                          void* __restrict__ Cv,
                                          void* __restrict__ Cv2,
                                          float oscale,
                                          u16* At, u16* Bt) {
    int tid = threadIdx.x, lane = tid & 63, wave = tid >> 6;
    int q = lane >> 4, l16 = lane & 15;
    constexpr int MI = (BN == 128) ? 2 : 1;
    int wm, wn;
    if constexpr (BN == 128) { wm = wave & 1; wn = wave >> 1; }
    else                     { wm = wave;     wn = 0; }
    int nBlk = bid / GY;
    int mBlk = bid - nBlk * GY;
    int nBase = nBlk * BN, mBase = mBlk * 64;
    f32x4 acc[MI][4] = {};

    for (int kk = 0; kk < 512; kk += 64) {
        __syncthreads();
#pragma unroll
        for (int t = 0; t < 2; ++t) {             // At: 512 chunk slots
            int c = tid + t * 256;
            int m = c >> 3, kc = (c & 7) ^ (m & 7);
            gl2lds16(&A[(size_t)(mBase + m) * 512 + kk + kc * 8], &At[c * 8]);
        }
#pragma unroll
        for (int t = 0; t < BN / 32; ++t) {       // Bt: BN*8 chunk slots
            int c = tid + t * 256;
            int m = c >> 3, kc = (c & 7) ^ (m & 7);
            gl2lds16(&WT[(size_t)(nBase + m) * 512 + kk + kc * 8], &Bt[c * 8]);
        }
        __syncthreads();
#pragma unroll
        for (int ds = 0; ds < 2; ++ds) {
            bf16x8 a[MI], b[4];
#pragma unroll
            for (int i = 0; i < MI; ++i) {
                int ma = (BN == 128 ? wm * 32 : wm * 16) + i * 16 + l16;
                a[i] = *(bf16x8*)(&At[ma * 64 + ((((ds << 2) + q) ^ (ma & 7)) << 3)]);
            }
#pragma unroll
            for (int j = 0; j < 4; ++j) {
                int nb = wn * 64 + j * 16 + l16;
                b[j] = *(bf16x8*)(&Bt[nb * 64 + ((((ds << 2) + q) ^ (nb & 7)) << 3)]);
            }
#pragma unroll
            for (int i = 0; i < MI; ++i)
#pragma unroll
                for (int j = 0; j < 4; ++j)
                    acc[i][j] = __builtin_amdgcn_mfma_f32_16x16x32_bf16(a[i], b[j], acc[i][j], 0, 0, 0);
        }
    }

    bool isK = (OM != 3) || (nBase < 512);
#pragma unroll
    for (int j = 0; j < 4; ++j) {
        int col = nBase + wn * 64 + j * 16 + l16;
        float bv;
        if constexpr (OM == 3) bv = isK ? bias[col] : bias2res[col - 512];
        else bv = bias[col];
#pragma unroll
        for (int i = 0; i < MI; ++i) {
#pragma unroll
            for (int r = 0; r < 4; ++r) {
                int row = mBase + (BN == 128 ? wm * 32 : wm * 16) + i * 16 + q * 4 + r;
                float v = acc[i][j][r] + bv;
                if constexpr (OM == 1) {
                    v += bias2res[(size_t)row * 512 + col];
                    ((float*)Cv)[(size_t)row * 512 + col] = v;
                } else if constexpr (OM == 0) {
                    ((u16*)Cv)[(size_t)row * 512 + col] = f2b(v * oscale);
                } else {
                    if (isK) {
                        ((u16*)Cv)[(size_t)row * 512 + col] = f2b(v);
                    } else {
                        int colv = col - 512;
                        int g = row >> 7, m2 = ((row & 127) << 3) + (colv >> 6), d = colv & 63;
                        ((u16*)Cv2)[(size_t)((g << 6) + d) * 1024 + m2] = f2b(v);
                    }
                }
            }
        }
    }
}

// ---------------------------------------------------------------------------
// Launch 2: Q-GEMM (blocks 0..1023) U pool (blocks 1024..2047). LDS 24 KB.
// ---------------------------------------------------------------------------
__global__ __launch_bounds__(256, 4) void qpool_kernel(const u16* __restrict__ xb,
                                                       const u16* __restrict__ wTq,
                                                       const float* __restrict__ b_q,
                                                       u16* __restrict__ Qw,
                                                       u16* __restrict__ xp) {
    __shared__ __align__(16) u16 At[64 * 64];
    __shared__ __align__(16) u16 Bt[128 * 64];
    int gid = blockIdx.x;
    if (gid < 1024) {
        gemm_body<0, 128, 256>(gid, xb, wTq, b_q, nullptr, Qw, nullptr, QSCALE, At, Bt);
    } else {
        pool_body((gid - 1024) * 256 + threadIdx.x, xb, xp);
    }
}

// Launch 3: fused K|V projection, tile 64x64 -> 1024 blocks = 4/CU.
__global__ __launch_bounds__(256, 4) void gemm_kv_kernel(const u16* __restrict__ xp,
                                                         const u16* __restrict__ wTkv,
                                                         const float* __restrict__ b_k,
                                                         const float* __restrict__ b_v,
                                                         u16* __restrict__ Kw,
                                                         u16* __restrict__ VwT) {
    __shared__ __align__(16) u16 At[64 * 64];
    __shared__ __align__(16) u16 Bt[64 * 64];
    gemm_body<3, 64, 64>(blockIdx.x, xp, wTkv, b_k, b_v, Kw, VwT, 1.0f, At, Bt);
}

// Launch 5: output projection + f32 residual.
__global__ __launch_bounds__(256, 4) void gemm_o_kernel(const u16* __restrict__ Ow,
                                                        const u16* __restrict__ wTo,
                                                        const float* __restrict__ b_o,
                                                        const float* __restrict__ xres,
                                                        float* __restrict__ out) {
    __shared__ __align__(16) u16 At[64 * 64];
    __shared__ __align__(16) u16 Bt[128 * 64];
    gemm_body<1, 128, 256>(blockIdx.x, Ow, wTo, b_o, xres, out, nullptr, 1.0f, At, Bt);
}

// ---------------------------------------------------------------------------
// Launch 4: flash attention, S^T formulation. QBLK=64, KVBLK=64 (this round:
// was 128/128 at 40 KB LDS -> grid 1024 AND LDS both capped occupancy at 4
// blocks/CU; attn is latency-bound on the QK->exp->Pt->PV chain with only
// 16 waves/CU of TLP). Now LDS = Kt 8K + VTs 8K + Pt 8K = 24 KB -> 6
// blocks/CU, grid 2048 -> slots actually fill (24 waves/CU). Per-wave work
// halves; swizzle keys keep the &7 form; registers drop (qf/oacc halve).
// VALU cut (exp2 builtin + cvt_pk), XCD pinning (g = blockIdx.x -> XCD =
// g&7), setprio around MFMA all kept.
// ---------------------------------------------------------------------------
__global__ __launch_bounds__(256, 6) void attn_kernel(const u16* __restrict__ Q,
                                                      const u16* __restrict__ K,
                                                      const u16* __restrict__ VT_g,
                                                      u16* __restrict__ O) {
    int g = blockIdx.x;       // XCD = g & 7 (round-robin by linear id)
    int qtile = blockIdx.y;   // 0..63
    const u16* Qg = Q + (size_t)g * 262144;
    const u16* Kg = K + (size_t)g * 65536;
    const u16* Vt = VT_g + (size_t)g * 65536;   // [d][m], pitch 1024
    u16* Og = O + (size_t)g * 262144;

    __shared__ __align__(16) u16 Kt[64 * 64];     // XOR-8 swizzled [m][d]
    __shared__ __align__(16) u16 VTs[64 * 64];    // XOR-8 swizzled [d][m]
    __shared__ __align__(16) u16 Pt[64 * 64];     // XOR-4dw swizzled [n][m]

    int tid = threadIdx.x, lane = tid & 63, wave = tid >> 6;
    int q = lane >> 4, l16 = lane & 15;
    int n0 = qtile * 64;
    int pkey = (l16 & 7) << 2;            // dword-XOR key for Pt
    int prow = (wave * 16 + l16) * 32;    // Pt row base (dwords)
    int* Pt32 = (int*)Pt;

    bf16x8 qf[2];
#pragma unroll
    for (int ds = 0; ds < 2; ++ds)
        qf[ds] = *(const bf16x8*)(
            &Qg[(size_t)(n0 + wave * 16 + l16) * 64 + ds * 32 + q * 8]);

    f32x4 oacc[4] = {};
    float rsum = 0.f;

    for (int kb = 0; kb < 16; ++kb) {
        __syncthreads();
#pragma unroll
        for (int t = 0; t < 2; ++t) {
            int c = tid + t * 256;                // slot 0..511
            {   // K tile: 64 m-rows x 64 d, XOR-8
                int m = c >> 3, kc = (c & 7) ^ (m & 7);
                gl2lds16(&Kg[(size_t)(kb * 64 + m) * 64 + kc * 8], &Kt[c * 8]);
            }
            {   // V^T tile: 64 d-rows x 64 m, XOR-8
                int d = c >> 3, mc = (c & 7) ^ (d & 7);
                gl2lds16(&Vt[(size_t)d * 1024 + kb * 64 + mc * 8], &VTs[c * 8]);
            }
        }
        __syncthreads();

        // S^T block; p = exp2(z); packed b64 write to Pt[n][m]
#pragma unroll
        for (int cb = 0; cb < 4; ++cb) {
            int m = cb * 16 + l16;
            bf16x8 kf0 = *(bf16x8*)(&Kt[m * 64 + ((q ^ (m & 7)) << 3)]);
            bf16x8 kf1 = *(bf16x8*)(&Kt[m * 64 + (((4 + q) ^ (m & 7)) << 3)]);
            f32x4 z = {};
            __builtin_amdgcn_s_setprio(1);
            z = __builtin_amdgcn_mfma_f32_16x16x32_bf16(kf0, qf[0], z, 0, 0, 0);
            z = __builtin_amdgcn_mfma_f32_16x16x32_bf16(kf1, qf[1], z, 0, 0, 0);
            __builtin_amdgcn_s_setprio(0);
            float p0 = __builtin_amdgcn_exp2f(z[0]);
            float p1 = __builtin_amdgcn_exp2f(z[1]);
            float p2 = __builtin_amdgcn_exp2f(z[2]);
            float p3 = __builtin_amdgcn_exp2f(z[3]);
            rsum += (p0 + p1) + (p2 + p3);
            unsigned w0, w1;
            asm("v_cvt_pk_bf16_f32 %0, %1, %2" : "=v"(w0) : "v"(p0), "v"(p1));
            asm("v_cvt_pk_bf16_f32 %0, %1, %2" : "=v"(w1) : "v"(p2), "v"(p3));
            int2 w;
            w.x = (int)w0;
            w.y = (int)w1;
            int pd = (cb * 8 + q * 2) ^ pkey;
            *(int2*)(&Pt32[prow + pd]) = w;
        }
        // O += P V (same wave wrote Pt rows; DS in-order, no barrier)
#pragma unroll
        for (int ds = 0; ds < 2; ++ds) {
            int pd = (ds * 16 + q * 4) ^ pkey;
            bf16x8 ap = *(bf16x8*)(&Pt32[prow + pd]);
            __builtin_amdgcn_s_setprio(1);
#pragma unroll
            for (int db = 0; db < 4; ++db) {
                int dd = db * 16 + l16;
                int jj = ds * 4 + q;
                bf16x8 vb = *(bf16x8*)(&VTs[dd * 64 + ((jj ^ (dd & 7)) << 3)]);
                oacc[db] = __builtin_amdgcn_mfma_f32_16x16x32_bf16(ap, vb, oacc[db], 0, 0, 0);
            }
            __builtin_amdgcn_s_setprio(0);
        }
    }

    // epilogue: rsum at row n=l16 (partial over quads) -> reduce over quads,
    // then fetch row (q*4+r)'s total via shfl, normalize, store.
    {
        float v = rsum;
        v += __shfl_xor(v, 16, 64);
        v += __shfl_xor(v, 32, 64);
        rsum = v;
    }
    float inv[4];
#pragma unroll
    for (int r = 0; r < 4; ++r)
        inv[r] = 1.f / __shfl(rsum, q * 4 + r, 64);
#pragma unroll
    for (int db = 0; db < 4; ++db)
#pragma unroll
        for (int r = 0; r < 4; ++r) {
            int row = n0 + wave * 16 + q * 4 + r;
            Og[(size_t)row * 64 + db * 16 + l16] = f2b(oacc[db][r] * inv[r]);
        }
}

// ---------------------------------------------------------------------------
extern "C" void kernel_launch(void* const* d_in, const int* in_sizes, int n_in,
                              void* d_out, int out_size, void* d_ws, size_t ws_size,
                              hipStream_t stream) {
    const float* x   = (const float*)d_in[0];
    const float* w_q = (const float*)d_in[1];
    const float* b_q = (const float*)d_in[2];
    const float* w_k = (const float*)d_in[3];
    const float* b_k = (const float*)d_in[4];
    const float* w_v = (const float*)d_in[5];
    const float* b_v = (const float*)d_in[6];
    const float* w_o = (const float*)d_in[7];
    const float* b_o = (const float*)d_in[8];
    float* out = (float*)d_out;

    char* ws = (char*)d_ws;
    u16* xb  = (u16*)(ws);                        // 16 MB (16384,512) bf16
    u16* xp  = (u16*)(ws + (16ull << 20));        //  4 MB (4096,512)
    u16* Qw  = (u16*)(ws + (20ull << 20));        // 16 MB (16384,512)
    u16* Kw  = (u16*)(ws + (36ull << 20));        //  4 MB (4096,512)
    u16* VwT = (u16*)(ws + (40ull << 20));        //  4 MB 32x(64,1024)
    u16* wT  = (u16*)(ws + (44ull << 20));        //  2 MB: 4 x 512x512 bf16
    u16* Ow  = xb;  // alias: xb's last readers (Q-GEMM+pool, L2) precede attn's write (L4)

    // L1: cvt U wtrans
    cvtw_kernel<<<8448, 256, 0, stream>>>(x, xb, w_q, w_k, w_v, w_o, wT);
    // L2: Q projection (scaled by log2(e)/8) U pool
    qpool_kernel<<<2048, 256, 0, stream>>>(xb, wT, b_q, Qw, xp);
    // L3: fused K|V projection
    gemm_kv_kernel<<<1024, 256, 0, stream>>>(xp, wT + 262144, b_k, b_v, Kw, VwT);
    // L4: attention: 32 groups (x: XCD-pinned) x 64 q-tiles (y)
    attn_kernel<<<dim3(32, 64), 256, 0, stream>>>(Qw, Kw, VwT, Ow);
    // L5: output projection + f32 residual
    gemm_o_kernel<<<1024, 256, 0, stream>>>(Ow, wT + 786432, b_o, x, out);
}